// Round 2
// baseline (3936.682 us; speedup 1.0000x reference)
//
#include <hip/hip_runtime.h>

#define B_ 128
#define T_ 31
#define E_ 512
#define H_ 512
#define V_ 10000
#define A_ 2048
#define TP1 32      // T+1
#define G4 2048     // 4*H
#define NHC 4096    // rows of [W_attn_H ; W_hh_perm]
#define MPRE 3968   // B*T

typedef unsigned short u16;
typedef __attribute__((ext_vector_type(8))) short bf16x8;
typedef __attribute__((ext_vector_type(4))) float f32x4;

__device__ __forceinline__ u16 f2b(float f) {
  union { float f; unsigned u; } x; x.f = f;
  unsigned r = x.u + 0x7fffu + ((x.u >> 16) & 1u);
  return (u16)(r >> 16);
}
__device__ __forceinline__ float sigmoidf_(float x) { return 1.f / (1.f + __expf(-x)); }

// ---------------- prep kernels ----------------

// xs_tb[t][b][e] bf16 : t=0 -> features, t>=1 -> embed[captions[b][t-1]]
__global__ __launch_bounds__(256) void prep_xs(
    u16* __restrict__ xs, const float* __restrict__ features,
    const int* __restrict__ captions, const float* __restrict__ embed) {
  int idx = blockIdx.x * 256 + threadIdx.x;       // < 32*128*512
  int e = idx & 511;
  int b = (idx >> 9) & 127;
  int t = idx >> 16;
  float v;
  if (t == 0) v = features[b * 512 + e];
  else        v = embed[(size_t)captions[b * 31 + (t - 1)] * 512 + e];
  xs[idx] = f2b(v);
}

__global__ __launch_bounds__(256) void cast_k(
    u16* __restrict__ dst, const float* __restrict__ src, int n) {
  int i = blockIdx.x * 256 + threadIdx.x;
  if (i < n) dst[i] = f2b(src[i]);
}

// gate-interleaved permutation: g' = j*4+gate  <->  g = gate*512+j
// W_ih_p[g'][e] = W_ih[gate*512+j][e]
__global__ __launch_bounds__(256) void prep_w_perm(
    u16* __restrict__ dst, const float* __restrict__ W) {
  int i = blockIdx.x * 256 + threadIdx.x;         // < 2048*512
  int gp = i >> 9, k = i & 511;
  int j = gp >> 2, gate = gp & 3;
  dst[i] = f2b(W[((size_t)gate * 512 + j) * 512 + k]);
}

// W_attnE[n][k] = W_attn[n][k] (k<512) ; Whc rows 0..2047 = W_attn[n][512+k]
__global__ __launch_bounds__(256) void prep_attn_w(
    u16* __restrict__ WattnE, u16* __restrict__ WhComb, const float* __restrict__ W_attn) {
  int i = blockIdx.x * 256 + threadIdx.x;         // < 2048*512
  int r = i >> 9, k = i & 511;
  WattnE[i] = f2b(W_attn[r * 1024 + k]);
  WhComb[i] = f2b(W_attn[r * 1024 + 512 + k]);
}

// W_attdE[e][k] = W_attd[e][k] (k<512)
__global__ __launch_bounds__(256) void prep_attdE(
    u16* __restrict__ dst, const float* __restrict__ W_attd) {
  int i = blockIdx.x * 256 + threadIdx.x;         // < 512*512
  int r = i >> 9, k = i & 511;
  dst[i] = f2b(W_attd[r * 2560 + k]);
}

// W_attdAT[a][e] = W_attd[e][512+a]
__global__ __launch_bounds__(256) void prep_attdAT(
    u16* __restrict__ dst, const float* __restrict__ W_attd) {
  int i = blockIdx.x * 256 + threadIdx.x;         // < 2048*512
  int a = i >> 9, e = i & 511;
  dst[i] = f2b(W_attd[(size_t)e * 2560 + 512 + a]);
}

// bias_p[j*4+gate] = b_ih[gate*512+j] + b_hh[gate*512+j]
__global__ __launch_bounds__(256) void prep_bias_p(
    float* __restrict__ dst, const float* __restrict__ a, const float* __restrict__ b) {
  int i = blockIdx.x * 256 + threadIdx.x;
  if (i < G4) {
    int j = i >> 2, gate = i & 3;
    int g = gate * 512 + j;
    dst[i] = a[g] + b[g];
  }
}

// ---------------- generic NT GEMM:  C[M,N] = A[M,K] * B[N,K]^T (+bias[n]) ----------------
template<bool OUT_BF16, bool ATOMIC, bool NGUARD>
__global__ __launch_bounds__(256) void gemm_nt(
    const u16* __restrict__ Ag, const u16* __restrict__ Bg,
    void* __restrict__ Cout, const float* __restrict__ bias,
    int N, int lda, int ldb, int ldc, int kChunk) {
  __shared__ __align__(16) u16 As[64 * 40];
  __shared__ __align__(16) u16 Bs[64 * 40];
  const int n0 = blockIdx.x * 64;
  const int m0 = blockIdx.y * 64;
  const int k0 = blockIdx.z * kChunk;
  const int tid  = threadIdx.x;
  const int wave = tid >> 6, lane = tid & 63;
  const int quad = lane >> 4, lq = lane & 15;
  const int srow = tid >> 2, sgrp = tid & 3;

  f32x4 acc[4] = {{0,0,0,0},{0,0,0,0},{0,0,0,0},{0,0,0,0}};
  const u16* aptr = Ag + (size_t)(m0 + srow) * lda + k0 + sgrp * 8;
  const u16* bptr = Bg + (size_t)(n0 + srow) * ldb + k0 + sgrp * 8;
  const bool bvalid = !NGUARD || (n0 + srow) < N;

  for (int kk = 0; kk < kChunk; kk += 32) {
    uint4 av = *(const uint4*)(aptr + kk);
    uint4 bv = make_uint4(0u, 0u, 0u, 0u);
    if (bvalid) bv = *(const uint4*)(bptr + kk);
    __syncthreads();
    *(uint4*)&As[srow * 40 + sgrp * 8] = av;
    *(uint4*)&Bs[srow * 40 + sgrp * 8] = bv;
    __syncthreads();
    bf16x8 af = *(const bf16x8*)&As[(wave * 16 + lq) * 40 + quad * 8];
#pragma unroll
    for (int j = 0; j < 4; ++j) {
      bf16x8 bfr = *(const bf16x8*)&Bs[(j * 16 + lq) * 40 + quad * 8];
      acc[j] = __builtin_amdgcn_mfma_f32_16x16x32_bf16(af, bfr, acc[j], 0, 0, 0);
    }
  }
  const int row = m0 + wave * 16 + quad * 4;
#pragma unroll
  for (int j = 0; j < 4; ++j) {
    int col = n0 + j * 16 + lq;
    if (NGUARD && col >= N) continue;
    float bval = bias ? bias[col] : 0.f;
#pragma unroll
    for (int r = 0; r < 4; ++r) {
      float v = acc[j][r] + bval;
      size_t ci = (size_t)(row + r) * ldc + col;
      if (OUT_BF16)      ((u16*)Cout)[ci] = f2b(v);
      else if (ATOMIC)   atomicAdd((float*)Cout + ci, v);
      else               ((float*)Cout)[ci] = v;
    }
  }
}

// ---------------- step-0 LSTM pointwise (permuted gate layout, c0=h0=0) ----------------
__global__ __launch_bounds__(256) void lstm0_pw(
    const float* __restrict__ g0, float* __restrict__ c_st, u16* __restrict__ h0) {
  int idx = blockIdx.x * 256 + threadIdx.x;   // < 128*512
  int b = idx >> 9, j = idx & 511;
  float4 g = *(const float4*)&g0[(size_t)b * 2048 + j * 4];
  float iv = sigmoidf_(g.x), gv = tanhf(g.z), ov = sigmoidf_(g.w);
  float c = iv * gv;                          // f * c0 = 0
  c_st[idx] = c;
  h0[idx] = f2b(ov * tanhf(c));
}

// ---------------- persistent recurrence kernel ----------------

__device__ __forceinline__ void grid_barrier(unsigned* ctr, unsigned target) {
  __syncthreads();                      // all WG stores drained (vmcnt 0 before s_barrier)
  if (threadIdx.x == 0) {
    __threadfence();                    // release: make WG writes device-visible
    __hip_atomic_fetch_add(ctr, 1u, __ATOMIC_RELAXED, __HIP_MEMORY_SCOPE_AGENT);
    while (__hip_atomic_load(ctr, __ATOMIC_RELAXED, __HIP_MEMORY_SCOPE_AGENT) < target)
      __builtin_amdgcn_s_sleep(1);
  }
  __syncthreads();
  __threadfence();                      // acquire: invalidate caches before reading peers' data
}

__global__ __launch_bounds__(256) void recurrence(
    const u16* __restrict__ Whc, const u16* __restrict__ Wc,
    const float* __restrict__ preA, const float* __restrict__ preG,
    const float* __restrict__ cnn, const float* __restrict__ c_init,
    u16* __restrict__ h_all, float* __restrict__ hW, u16* __restrict__ att,
    unsigned* __restrict__ ctr) {
  __shared__ float red[4 * 64 * 17];    // K-split partial gates, pad 17 vs bank conflicts
  __shared__ float wsum[4];
  const int w = blockIdx.x;             // 0..255, one WG per CU
  const int tid = threadIdx.x;
  const int wv = tid >> 6, lane = tid & 63;
  const int quad = lane >> 4, lq = lane & 15;
  // P3 / LSTM ownership (fixed across steps; c lives in a register)
  const int mhalf = w >> 7, cg = w & 127;
  const int bl = tid >> 2, jj = tid & 3;
  const int b_own = mhalf * 64 + bl;
  const int j_own = cg * 4 + jj;
  float c_reg = c_init[b_own * 512 + j_own];
  unsigned bar = 0;

  for (int t = 1; t <= T_; ++t) {
    const u16* hp = h_all + (size_t)(t - 1) * (B_ * H_);
    // ---- P1: hW[:, w*16 .. w*16+16) = h_{t-1} @ Whc_rows^T ----
    {
      const int n0 = w * 16;
      const int m0 = wv * 32;
      const u16* a0 = hp + (size_t)(m0 + lq) * 512 + quad * 8;
      const u16* a1 = a0 + 16 * 512;
      const u16* bp = Whc + (size_t)(n0 + lq) * 512 + quad * 8;
      f32x4 acc0 = {0,0,0,0}, acc1 = {0,0,0,0};
      for (int kk = 0; kk < 16; ++kk) {
        bf16x8 bf  = *(const bf16x8*)(bp + kk * 32);
        bf16x8 af0 = *(const bf16x8*)(a0 + kk * 32);
        bf16x8 af1 = *(const bf16x8*)(a1 + kk * 32);
        acc0 = __builtin_amdgcn_mfma_f32_16x16x32_bf16(af0, bf, acc0, 0, 0, 0);
        acc1 = __builtin_amdgcn_mfma_f32_16x16x32_bf16(af1, bf, acc1, 0, 0, 0);
      }
      float* o0 = hW + (size_t)(m0 + quad * 4) * 4096 + n0 + lq;
#pragma unroll
      for (int r = 0; r < 4; ++r) o0[(size_t)r * 4096] = acc0[r];
      float* o1 = hW + (size_t)(m0 + 16 + quad * 4) * 4096 + n0 + lq;
#pragma unroll
      for (int r = 0; r < 4; ++r) o1[(size_t)r * 4096] = acc1[r];
    }
    grid_barrier(ctr, (++bar) * 256);
    // ---- P2: softmax + attended, WGs 0..127 own row b=w ----
    if (w < 128) {
      const float* pA  = preA + ((size_t)(t - 1) * 128 + w) * 2048;
      const float* hWr = hW + (size_t)w * 4096;
      float e8[8]; float s = 0.f;
#pragma unroll
      for (int i = 0; i < 8; ++i) {
        int n = tid + i * 256;
        e8[i] = __expf(pA[n] + hWr[n]);
        s += e8[i];
      }
#pragma unroll
      for (int o = 32; o > 0; o >>= 1) s += __shfl_down(s, o);
      if (lane == 0) wsum[wv] = s;
      __syncthreads();
      float inv = 1.f / (wsum[0] + wsum[1] + wsum[2] + wsum[3]);
#pragma unroll
      for (int i = 0; i < 8; ++i) {
        int n = tid + i * 256;
        att[(size_t)w * 2048 + n] = f2b(cnn[(size_t)w * 2048 + n] * e8[i] * inv);
      }
    }
    grid_barrier(ctr, (++bar) * 256);
    // ---- P3: gates GEMM (per-wave K-split) + LDS reduce + fused LSTM ----
    {
      const u16* ab = att + (size_t)(mhalf * 64 + lq) * 2048 + wv * 512 + quad * 8;
      const u16* bp = Wc + (size_t)(cg * 16 + lq) * 2048 + wv * 512 + quad * 8;
      f32x4 acc[4] = {{0,0,0,0},{0,0,0,0},{0,0,0,0},{0,0,0,0}};
      for (int kk = 0; kk < 16; ++kk) {
        bf16x8 bf = *(const bf16x8*)(bp + kk * 32);
#pragma unroll
        for (int mt = 0; mt < 4; ++mt) {
          bf16x8 af = *(const bf16x8*)(ab + (size_t)mt * 16 * 2048 + kk * 32);
          acc[mt] = __builtin_amdgcn_mfma_f32_16x16x32_bf16(af, bf, acc[mt], 0, 0, 0);
        }
      }
#pragma unroll
      for (int mt = 0; mt < 4; ++mt)
#pragma unroll
        for (int r = 0; r < 4; ++r)
          red[(wv * 64 + mt * 16 + quad * 4 + r) * 17 + lq] = acc[mt][r];
      __syncthreads();
      float s0 = 0.f, s1 = 0.f, s2 = 0.f, s3 = 0.f;
#pragma unroll
      for (int kw = 0; kw < 4; ++kw) {
        const float* rr = &red[(kw * 64 + bl) * 17 + jj * 4];
        s0 += rr[0]; s1 += rr[1]; s2 += rr[2]; s3 += rr[3];
      }
      const float4 pg = *(const float4*)&preG[((size_t)(t - 1) * 128 + b_own) * 2048 + cg * 16 + jj * 4];
      const float4 hg = *(const float4*)&hW[(size_t)b_own * 4096 + 2048 + cg * 16 + jj * 4];
      float iv = sigmoidf_(s0 + pg.x + hg.x);
      float fv = sigmoidf_(s1 + pg.y + hg.y);
      float gv = tanhf(s2 + pg.z + hg.z);
      float ov = sigmoidf_(s3 + pg.w + hg.w);
      c_reg = fv * c_reg + iv * gv;
      h_all[(size_t)t * (B_ * H_) + b_own * 512 + j_own] = f2b(ov * tanhf(c_reg));
    }
    grid_barrier(ctr, (++bar) * 256);
  }
}

// ---------------- host ----------------

extern "C" void kernel_launch(void* const* d_in, const int* in_sizes, int n_in,
                              void* d_out, int out_size, void* d_ws, size_t ws_size,
                              hipStream_t stream) {
  (void)in_sizes; (void)n_in; (void)out_size; (void)ws_size;
  const float* features = (const float*)d_in[0];
  const float* cnn      = (const float*)d_in[1];
  const int*   captions = (const int*)d_in[2];
  const float* embed    = (const float*)d_in[4];
  const float* W_ih     = (const float*)d_in[5];
  const float* W_hh     = (const float*)d_in[6];
  const float* b_ih     = (const float*)d_in[7];
  const float* b_hh     = (const float*)d_in[8];
  const float* W_attn   = (const float*)d_in[9];
  const float* b_attn   = (const float*)d_in[10];
  const float* W_attd   = (const float*)d_in[11];
  const float* b_attd   = (const float*)d_in[12];
  const float* W_out    = (const float*)d_in[13];
  const float* b_out    = (const float*)d_in[14];

  char* ws = (char*)d_ws;
  size_t off = 0;
  auto alloc = [&](size_t bytes) { void* p = ws + off; off += (bytes + 255) & ~255UL; return p; };
  u16*   xs_tb   = (u16*)  alloc((size_t)TP1 * B_ * E_ * 2);
  u16*   h_all   = (u16*)  alloc((size_t)TP1 * B_ * H_ * 2);
  u16*   Whc     = (u16*)  alloc((size_t)NHC * H_ * 2);        // rows 0..2047 attn, 2048.. gate-perm W_hh
  u16*   W_ih_p  = (u16*)  alloc((size_t)G4 * E_ * 2);         // gate-interleaved
  u16*   W_attnE = (u16*)  alloc((size_t)A_ * E_ * 2);
  u16*   W_attdE = (u16*)  alloc((size_t)E_ * E_ * 2);
  u16*   W_attdAT= (u16*)  alloc((size_t)A_ * E_ * 2);
  u16*   W_out_b = (u16*)  alloc((size_t)V_ * H_ * 2);
  u16*   Wc      = (u16*)  alloc((size_t)G4 * A_ * 2);         // gate-interleaved rows
  u16*   pre_x2  = (u16*)  alloc((size_t)MPRE * E_ * 2);
  float* c_st    = (float*)alloc((size_t)B_ * H_ * 4);
  float* hW      = (float*)alloc((size_t)B_ * NHC * 4);        // also reused as g0 buffer
  u16*   att     = (u16*)  alloc((size_t)B_ * A_ * 2);
  float* bias_p  = (float*)alloc((size_t)G4 * 4);
  unsigned* ctr  = (unsigned*)alloc(256);

  // big precompute arrays live in d_out (dead before final GEMM overwrites it)
  float* preA = (float*)d_out;                 // [31,128,2048] fp32
  float* preG = preA + (size_t)MPRE * A_;      // [31,128,2048] fp32, gate-interleaved
  float* logits = (float*)d_out;

  // --- prep ---
  prep_xs<<<(TP1 * B_ * E_) / 256, 256, 0, stream>>>(xs_tb, features, captions, embed);
  prep_w_perm<<<(G4 * E_) / 256, 256, 0, stream>>>(W_ih_p, W_ih);
  prep_w_perm<<<(G4 * H_) / 256, 256, 0, stream>>>(Whc + (size_t)A_ * H_, W_hh);
  cast_k<<<(V_ * H_) / 256, 256, 0, stream>>>(W_out_b, W_out, V_ * H_);
  prep_attn_w<<<(A_ * E_) / 256, 256, 0, stream>>>(W_attnE, Whc, W_attn);
  prep_attdE<<<(E_ * E_) / 256, 256, 0, stream>>>(W_attdE, W_attd);
  prep_attdAT<<<(A_ * E_) / 256, 256, 0, stream>>>(W_attdAT, W_attd);
  prep_bias_p<<<G4 / 256, 256, 0, stream>>>(bias_p, b_ih, b_hh);

  // --- precompute GEMMs ---
  gemm_nt<true, false, false><<<dim3(A_ / 64, G4 / 64, 1), 256, 0, stream>>>(
      W_ih_p, W_attdAT, Wc, nullptr, A_, 512, 512, A_, 512);
  gemm_nt<false, false, false><<<dim3(A_ / 64, MPRE / 64, 1), 256, 0, stream>>>(
      xs_tb + (size_t)B_ * E_, W_attnE, preA, b_attn, A_, 512, 512, A_, 512);
  gemm_nt<true, false, false><<<dim3(E_ / 64, MPRE / 64, 1), 256, 0, stream>>>(
      xs_tb + (size_t)B_ * E_, W_attdE, pre_x2, b_attd, E_, 512, 512, E_, 512);
  gemm_nt<false, false, false><<<dim3(G4 / 64, MPRE / 64, 1), 256, 0, stream>>>(
      pre_x2, W_ih_p, preG, bias_p, G4, 512, 512, G4, 512);
  gemm_nt<false, false, false><<<dim3(G4 / 64, B_ / 64, 1), 256, 0, stream>>>(
      xs_tb, W_ih_p, hW, bias_p, G4, 512, 512, G4, 512);
  lstm0_pw<<<(B_ * H_) / 256, 256, 0, stream>>>(hW, c_st, h_all);

  // --- persistent recurrence (256 WGs <= guaranteed co-residency) ---
  hipMemsetAsync(ctr, 0, sizeof(unsigned), stream);
  recurrence<<<dim3(256), dim3(256), 0, stream>>>(
      Whc, Wc, preA, preG, cnn, c_st, h_all, hW, att, ctr);

  // --- final projection: logits = hidden @ W_out^T + b_out ---
  gemm_nt<false, false, true><<<dim3((V_ + 63) / 64, (TP1 * B_) / 64, 1), 256, 0, stream>>>(
      h_all, W_out_b, logits, b_out, V_, 512, 512, V_, 512);
}

// Round 3
// 1129.892 us; speedup vs baseline: 3.4841x; 3.4841x over previous
//
#include <hip/hip_runtime.h>

#define B_ 128
#define T_ 31
#define E_ 512
#define H_ 512
#define V_ 10000
#define A_ 2048
#define TP1 32      // T+1
#define G4 2048     // 4*H
#define NHC 4096    // rows of [W_attn_H ; W_hh_perm]
#define MPRE 3968   // B*T
#define BH (B_ * H_)

typedef unsigned short u16;
typedef __attribute__((ext_vector_type(8))) short bf16x8;
typedef __attribute__((ext_vector_type(4))) float f32x4;

__device__ __forceinline__ u16 f2b(float f) {
  union { float f; unsigned u; } x; x.f = f;
  unsigned r = x.u + 0x7fffu + ((x.u >> 16) & 1u);
  return (u16)(r >> 16);
}
__device__ __forceinline__ float sigmoidf_(float x) { return 1.f / (1.f + __expf(-x)); }

// ---------------- prep kernels ----------------

__global__ __launch_bounds__(256) void prep_xs(
    u16* __restrict__ xs, const float* __restrict__ features,
    const int* __restrict__ captions, const float* __restrict__ embed) {
  int idx = blockIdx.x * 256 + threadIdx.x;       // < 32*128*512
  int e = idx & 511;
  int b = (idx >> 9) & 127;
  int t = idx >> 16;
  float v;
  if (t == 0) v = features[b * 512 + e];
  else        v = embed[(size_t)captions[b * 31 + (t - 1)] * 512 + e];
  xs[idx] = f2b(v);
}

__global__ __launch_bounds__(256) void cast_k(
    u16* __restrict__ dst, const float* __restrict__ src, int n) {
  int i = blockIdx.x * 256 + threadIdx.x;
  if (i < n) dst[i] = f2b(src[i]);
}

// gate-interleaved permutation: g' = j*4+gate  <->  g = gate*512+j
__global__ __launch_bounds__(256) void prep_w_perm(
    u16* __restrict__ dst, const float* __restrict__ W) {
  int i = blockIdx.x * 256 + threadIdx.x;         // < 2048*512
  int gp = i >> 9, k = i & 511;
  int j = gp >> 2, gate = gp & 3;
  dst[i] = f2b(W[((size_t)gate * 512 + j) * 512 + k]);
}

// W_attnE[n][k] = W_attn[n][k] (k<512) ; Whc rows 0..2047 = W_attn[n][512+k]
__global__ __launch_bounds__(256) void prep_attn_w(
    u16* __restrict__ WattnE, u16* __restrict__ WhComb, const float* __restrict__ W_attn) {
  int i = blockIdx.x * 256 + threadIdx.x;         // < 2048*512
  int r = i >> 9, k = i & 511;
  WattnE[i] = f2b(W_attn[r * 1024 + k]);
  WhComb[i] = f2b(W_attn[r * 1024 + 512 + k]);
}

__global__ __launch_bounds__(256) void prep_attdE(
    u16* __restrict__ dst, const float* __restrict__ W_attd) {
  int i = blockIdx.x * 256 + threadIdx.x;         // < 512*512
  int r = i >> 9, k = i & 511;
  dst[i] = f2b(W_attd[r * 2560 + k]);
}

__global__ __launch_bounds__(256) void prep_attdAT(
    u16* __restrict__ dst, const float* __restrict__ W_attd) {
  int i = blockIdx.x * 256 + threadIdx.x;         // < 2048*512
  int a = i >> 9, e = i & 511;
  dst[i] = f2b(W_attd[(size_t)e * 2560 + 512 + a]);
}

// bias_p[j*4+gate] = b_ih[gate*512+j] + b_hh[gate*512+j]
__global__ __launch_bounds__(256) void prep_bias_p(
    float* __restrict__ dst, const float* __restrict__ a, const float* __restrict__ b) {
  int i = blockIdx.x * 256 + threadIdx.x;
  if (i < G4) {
    int j = i >> 2, gate = i & 3;
    int g = gate * 512 + j;
    dst[i] = a[g] + b[g];
  }
}

// ---------------- 64x64-tile NT GEMM (small M):  C = A*B^T (+bias) ----------------
template<bool OUT_BF16>
__global__ __launch_bounds__(256) void gemm_nt(
    const u16* __restrict__ Ag, const u16* __restrict__ Bg,
    void* __restrict__ Cout, const float* __restrict__ bias,
    int lda, int ldb, int ldc, int kTot) {
  __shared__ __align__(16) u16 As[64 * 40];
  __shared__ __align__(16) u16 Bs[64 * 40];
  const int n0 = blockIdx.x * 64;
  const int m0 = blockIdx.y * 64;
  const int tid  = threadIdx.x;
  const int wave = tid >> 6, lane = tid & 63;
  const int quad = lane >> 4, lq = lane & 15;
  const int srow = tid >> 2, sgrp = tid & 3;

  f32x4 acc[4] = {{0,0,0,0},{0,0,0,0},{0,0,0,0},{0,0,0,0}};
  const u16* aptr = Ag + (size_t)(m0 + srow) * lda + sgrp * 8;
  const u16* bptr = Bg + (size_t)(n0 + srow) * ldb + sgrp * 8;

  for (int kk = 0; kk < kTot; kk += 32) {
    uint4 av = *(const uint4*)(aptr + kk);
    uint4 bv = *(const uint4*)(bptr + kk);
    __syncthreads();
    *(uint4*)&As[srow * 40 + sgrp * 8] = av;
    *(uint4*)&Bs[srow * 40 + sgrp * 8] = bv;
    __syncthreads();
    bf16x8 af = *(const bf16x8*)&As[(wave * 16 + lq) * 40 + quad * 8];
#pragma unroll
    for (int j = 0; j < 4; ++j) {
      bf16x8 bfr = *(const bf16x8*)&Bs[(j * 16 + lq) * 40 + quad * 8];
      acc[j] = __builtin_amdgcn_mfma_f32_16x16x32_bf16(af, bfr, acc[j], 0, 0, 0);
    }
  }
  const int row = m0 + wave * 16 + quad * 4;
#pragma unroll
  for (int j = 0; j < 4; ++j) {
    int col = n0 + j * 16 + lq;
    float bval = bias ? bias[col] : 0.f;
#pragma unroll
    for (int r = 0; r < 4; ++r) {
      float v = acc[j][r] + bval;
      size_t ci = (size_t)(row + r) * ldc + col;
      if (OUT_BF16) ((u16*)Cout)[ci] = f2b(v);
      else          ((float*)Cout)[ci] = v;
    }
  }
}

// ---------------- 128x128-tile NT GEMM, K=512:  C = A*B^T (+bias) ----------------
// 4 waves in 2x2; each wave 64x64 via 4x4 MFMA tiles. 16 MFMA + 8 ds_read_b128/iter.
template<bool OUT_BF16, bool NGUARD>
__global__ __launch_bounds__(256) void gemm128(
    const u16* __restrict__ Ag, const u16* __restrict__ Bg,
    void* __restrict__ Cout, const float* __restrict__ bias,
    int N, int lda, int ldb, int ldc) {
  __shared__ __align__(16) u16 As[128 * 40];
  __shared__ __align__(16) u16 Bs[128 * 40];
  const int n0 = blockIdx.x * 128;
  const int m0 = blockIdx.y * 128;
  const int tid = threadIdx.x;
  const int wave = tid >> 6, lane = tid & 63;
  const int quad = lane >> 4, lq = lane & 15;
  const int wr = wave >> 1, wc = wave & 1;
  const int r0 = tid >> 2, kg0 = tid & 3;

  f32x4 acc[4][4] = {};
  const u16* ap0 = Ag + (size_t)(m0 + r0) * lda + kg0 * 8;
  const u16* ap1 = Ag + (size_t)(m0 + 64 + r0) * lda + kg0 * 8;
  const int brow0 = n0 + r0, brow1 = n0 + 64 + r0;
  const u16* bp0 = Bg + (size_t)brow0 * ldb + kg0 * 8;
  const u16* bp1 = Bg + (size_t)brow1 * ldb + kg0 * 8;
  const bool bok0 = !NGUARD || brow0 < N;
  const bool bok1 = !NGUARD || brow1 < N;

  for (int k0 = 0; k0 < 512; k0 += 32) {
    uint4 a0 = *(const uint4*)(ap0 + k0);
    uint4 a1 = *(const uint4*)(ap1 + k0);
    uint4 b0 = bok0 ? *(const uint4*)(bp0 + k0) : make_uint4(0u,0u,0u,0u);
    uint4 b1 = bok1 ? *(const uint4*)(bp1 + k0) : make_uint4(0u,0u,0u,0u);
    __syncthreads();
    *(uint4*)&As[r0 * 40 + kg0 * 8] = a0;
    *(uint4*)&As[(64 + r0) * 40 + kg0 * 8] = a1;
    *(uint4*)&Bs[r0 * 40 + kg0 * 8] = b0;
    *(uint4*)&Bs[(64 + r0) * 40 + kg0 * 8] = b1;
    __syncthreads();
    bf16x8 afr[4], bfr[4];
#pragma unroll
    for (int mi = 0; mi < 4; ++mi)
      afr[mi] = *(const bf16x8*)&As[(wr * 64 + mi * 16 + lq) * 40 + quad * 8];
#pragma unroll
    for (int ni = 0; ni < 4; ++ni)
      bfr[ni] = *(const bf16x8*)&Bs[(wc * 64 + ni * 16 + lq) * 40 + quad * 8];
#pragma unroll
    for (int ni = 0; ni < 4; ++ni)
#pragma unroll
      for (int mi = 0; mi < 4; ++mi)
        acc[mi][ni] = __builtin_amdgcn_mfma_f32_16x16x32_bf16(afr[mi], bfr[ni], acc[mi][ni], 0, 0, 0);
  }
#pragma unroll
  for (int ni = 0; ni < 4; ++ni) {
    int col = n0 + wc * 64 + ni * 16 + lq;
    if (NGUARD && col >= N) continue;
    float bval = bias ? bias[col] : 0.f;
#pragma unroll
    for (int mi = 0; mi < 4; ++mi) {
      int row = m0 + wr * 64 + mi * 16 + quad * 4;
#pragma unroll
      for (int r = 0; r < 4; ++r) {
        float v = acc[mi][ni][r] + bval;
        size_t ci = (size_t)(row + r) * ldc + col;
        if (OUT_BF16) ((u16*)Cout)[ci] = f2b(v);
        else          ((float*)Cout)[ci] = v;
      }
    }
  }
}

// ---------------- step-0 LSTM pointwise (permuted gate layout, c0=h0=0) ----------------
__global__ __launch_bounds__(256) void lstm0_pw(
    const float* __restrict__ g0, float* __restrict__ c_st, u16* __restrict__ h0) {
  int idx = blockIdx.x * 256 + threadIdx.x;   // < 128*512
  int b = idx >> 9, j = idx & 511;
  float4 g = *(const float4*)&g0[(size_t)b * 2048 + j * 4];
  float iv = sigmoidf_(g.x), gv = tanhf(g.z), ov = sigmoidf_(g.w);
  float c = iv * gv;
  c_st[idx] = c;
  h0[idx] = f2b(ov * tanhf(c));
}

// ---------------- per-step K1: hW GEMM + fused exp/attended epilogue ----------------
// grid (64, 2): n0 = bx*64 over 4096 cols of [W_attn_H ; W_hh_perm], m0 = by*64.
// attn half (n0<2048): att_un = cnn*exp(preA+score) bf16, rowsum += partial e-sums.
// hh half: hWhh fp32 store (gate-interleaved cols).
__global__ __launch_bounds__(256) void step_hw(
    const u16* __restrict__ h_prev, const u16* __restrict__ Whc,
    const float* __restrict__ preA_t, const float* __restrict__ cnn,
    u16* __restrict__ att, float* __restrict__ hWhh, float* __restrict__ rowsum_t) {
  __shared__ __align__(16) u16 As[64 * 72];
  __shared__ __align__(16) u16 Bs[64 * 72];
  const int n0 = blockIdx.x * 64;
  const int m0 = blockIdx.y * 64;
  const int tid = threadIdx.x;
  const int wave = tid >> 6, lane = tid & 63;
  const int quad = lane >> 4, lq = lane & 15;
  const int sr0 = tid >> 3, sg0 = tid & 7;          // idx=tid
  const int sr1 = (tid + 256) >> 3, sg1 = tid & 7;  // idx=tid+256

  f32x4 acc[4] = {{0,0,0,0},{0,0,0,0},{0,0,0,0},{0,0,0,0}};
  for (int k0 = 0; k0 < 512; k0 += 64) {
    uint4 a0 = *(const uint4*)(h_prev + (size_t)(m0 + sr0) * 512 + k0 + sg0 * 8);
    uint4 b0 = *(const uint4*)(Whc + (size_t)(n0 + sr0) * 512 + k0 + sg0 * 8);
    uint4 a1 = *(const uint4*)(h_prev + (size_t)(m0 + sr1) * 512 + k0 + sg1 * 8);
    uint4 b1 = *(const uint4*)(Whc + (size_t)(n0 + sr1) * 512 + k0 + sg1 * 8);
    __syncthreads();
    *(uint4*)&As[sr0 * 72 + sg0 * 8] = a0;
    *(uint4*)&Bs[sr0 * 72 + sg0 * 8] = b0;
    *(uint4*)&As[sr1 * 72 + sg1 * 8] = a1;
    *(uint4*)&Bs[sr1 * 72 + sg1 * 8] = b1;
    __syncthreads();
#pragma unroll
    for (int h = 0; h < 2; ++h) {
      bf16x8 af = *(const bf16x8*)&As[(wave * 16 + lq) * 72 + h * 32 + quad * 8];
#pragma unroll
      for (int j = 0; j < 4; ++j) {
        bf16x8 bfr = *(const bf16x8*)&Bs[(j * 16 + lq) * 72 + h * 32 + quad * 8];
        acc[j] = __builtin_amdgcn_mfma_f32_16x16x32_bf16(af, bfr, acc[j], 0, 0, 0);
      }
    }
  }
  const int row0 = m0 + wave * 16 + quad * 4;
  if (n0 < 2048) {
    float rs[4] = {0.f, 0.f, 0.f, 0.f};
#pragma unroll
    for (int j = 0; j < 4; ++j) {
      int col = n0 + j * 16 + lq;
#pragma unroll
      for (int r = 0; r < 4; ++r) {
        size_t ix = (size_t)(row0 + r) * 2048 + col;
        float e = __expf(acc[j][r] + preA_t[ix]);
        att[ix] = f2b(cnn[ix] * e);
        rs[r] += e;
      }
    }
#pragma unroll
    for (int off = 1; off < 16; off <<= 1)
#pragma unroll
      for (int r = 0; r < 4; ++r) rs[r] += __shfl_xor(rs[r], off);
    if (lq == 0)
#pragma unroll
      for (int r = 0; r < 4; ++r) atomicAdd(&rowsum_t[row0 + r], rs[r]);
  } else {
#pragma unroll
    for (int j = 0; j < 4; ++j) {
      int col = n0 - 2048 + j * 16 + lq;
#pragma unroll
      for (int r = 0; r < 4; ++r)
        hWhh[(size_t)(row0 + r) * 2048 + col] = acc[j][r];
    }
  }
}

// ---------------- per-step K2: gates GEMM (wave K-split) + fused LSTM ----------------
// grid (128, 2): cg = bx owns 16 gate-cols; mhalf = by owns 64 batch rows.
__global__ __launch_bounds__(256) void step_gates(
    const u16* __restrict__ att, const u16* __restrict__ Wc,
    const float* __restrict__ preG_t, const float* __restrict__ hWhh,
    const float* __restrict__ rowsum_t, float* __restrict__ c_st,
    u16* __restrict__ h_out) {
  __shared__ float red[4 * 64 * 17];
  const int cg = blockIdx.x;
  const int mhalf = blockIdx.y;
  const int tid = threadIdx.x;
  const int wv = tid >> 6, lane = tid & 63;
  const int quad = lane >> 4, lq = lane & 15;

  const u16* ab = att + (size_t)(mhalf * 64 + lq) * 2048 + wv * 512 + quad * 8;
  const u16* bp = Wc + (size_t)(cg * 16 + lq) * 2048 + wv * 512 + quad * 8;
  f32x4 acc[4] = {{0,0,0,0},{0,0,0,0},{0,0,0,0},{0,0,0,0}};
  for (int kk = 0; kk < 16; ++kk) {
    bf16x8 bf = *(const bf16x8*)(bp + kk * 32);
#pragma unroll
    for (int mt = 0; mt < 4; ++mt) {
      bf16x8 af = *(const bf16x8*)(ab + (size_t)mt * 16 * 2048 + kk * 32);
      acc[mt] = __builtin_amdgcn_mfma_f32_16x16x32_bf16(af, bf, acc[mt], 0, 0, 0);
    }
  }
#pragma unroll
  for (int mt = 0; mt < 4; ++mt)
#pragma unroll
    for (int r = 0; r < 4; ++r)
      red[(wv * 64 + mt * 16 + quad * 4 + r) * 17 + lq] = acc[mt][r];
  __syncthreads();
  const int bl = tid >> 2, jj = tid & 3;
  const int b_own = mhalf * 64 + bl;
  const int j_own = cg * 4 + jj;
  float s0 = 0.f, s1 = 0.f, s2 = 0.f, s3 = 0.f;
#pragma unroll
  for (int kw = 0; kw < 4; ++kw) {
    const float* rr = &red[(kw * 64 + bl) * 17 + jj * 4];
    s0 += rr[0]; s1 += rr[1]; s2 += rr[2]; s3 += rr[3];
  }
  float inv_s = 1.f / rowsum_t[b_own];
  const float4 pg = *(const float4*)&preG_t[(size_t)b_own * 2048 + cg * 16 + jj * 4];
  const float4 hg = *(const float4*)&hWhh[(size_t)b_own * 2048 + cg * 16 + jj * 4];
  float iv = sigmoidf_(s0 * inv_s + pg.x + hg.x);
  float fv = sigmoidf_(s1 * inv_s + pg.y + hg.y);
  float gv = tanhf(s2 * inv_s + pg.z + hg.z);
  float ov = sigmoidf_(s3 * inv_s + pg.w + hg.w);
  int ci = b_own * 512 + j_own;
  float c = fv * c_st[ci] + iv * gv;
  c_st[ci] = c;
  h_out[ci] = f2b(ov * tanhf(c));
}

// ---------------- host ----------------

extern "C" void kernel_launch(void* const* d_in, const int* in_sizes, int n_in,
                              void* d_out, int out_size, void* d_ws, size_t ws_size,
                              hipStream_t stream) {
  (void)in_sizes; (void)n_in; (void)out_size; (void)ws_size;
  const float* features = (const float*)d_in[0];
  const float* cnn      = (const float*)d_in[1];
  const int*   captions = (const int*)d_in[2];
  const float* embed    = (const float*)d_in[4];
  const float* W_ih     = (const float*)d_in[5];
  const float* W_hh     = (const float*)d_in[6];
  const float* b_ih     = (const float*)d_in[7];
  const float* b_hh     = (const float*)d_in[8];
  const float* W_attn   = (const float*)d_in[9];
  const float* b_attn   = (const float*)d_in[10];
  const float* W_attd   = (const float*)d_in[11];
  const float* b_attd   = (const float*)d_in[12];
  const float* W_out    = (const float*)d_in[13];
  const float* b_out    = (const float*)d_in[14];

  char* ws = (char*)d_ws;
  size_t off = 0;
  auto alloc = [&](size_t bytes) { void* p = ws + off; off += (bytes + 255) & ~255UL; return p; };
  u16*   xs_tb   = (u16*)  alloc((size_t)TP1 * B_ * E_ * 2);
  u16*   h_all   = (u16*)  alloc((size_t)TP1 * B_ * H_ * 2);
  u16*   Whc     = (u16*)  alloc((size_t)NHC * H_ * 2);   // rows 0..2047 attn_H, 2048.. gate-perm W_hh
  u16*   W_ih_p  = (u16*)  alloc((size_t)G4 * E_ * 2);    // gate-interleaved
  u16*   W_attnE = (u16*)  alloc((size_t)A_ * E_ * 2);
  u16*   W_attdE = (u16*)  alloc((size_t)E_ * E_ * 2);
  u16*   W_attdAT= (u16*)  alloc((size_t)A_ * E_ * 2);
  u16*   W_out_b = (u16*)  alloc((size_t)V_ * H_ * 2);
  u16*   Wc      = (u16*)  alloc((size_t)G4 * A_ * 2);    // gate-interleaved rows
  u16*   pre_x2  = (u16*)  alloc((size_t)MPRE * E_ * 2);
  float* c_st    = (float*)alloc((size_t)B_ * H_ * 4);
  float* hWhh    = (float*)alloc((size_t)B_ * G4 * 4);    // per-step hh-half scores; also g0 buffer
  u16*   att     = (u16*)  alloc((size_t)B_ * A_ * 2);    // unnormalized cnn*e, bf16
  float* rowsum  = (float*)alloc((size_t)T_ * B_ * 4);    // per-step softmax denominators
  float* bias_p  = (float*)alloc((size_t)G4 * 4);

  // big precompute arrays live in d_out (dead before final GEMM overwrites it)
  float* preA = (float*)d_out;                 // [31,128,2048] fp32
  float* preG = preA + (size_t)MPRE * A_;      // [31,128,2048] fp32, gate-interleaved
  float* logits = (float*)d_out;

  // --- prep ---
  prep_xs<<<(TP1 * B_ * E_) / 256, 256, 0, stream>>>(xs_tb, features, captions, embed);
  prep_w_perm<<<(G4 * E_) / 256, 256, 0, stream>>>(W_ih_p, W_ih);
  prep_w_perm<<<(G4 * H_) / 256, 256, 0, stream>>>(Whc + (size_t)A_ * H_, W_hh);
  cast_k<<<(V_ * H_) / 256, 256, 0, stream>>>(W_out_b, W_out, V_ * H_);
  prep_attn_w<<<(A_ * E_) / 256, 256, 0, stream>>>(W_attnE, Whc, W_attn);
  prep_attdE<<<(E_ * E_) / 256, 256, 0, stream>>>(W_attdE, W_attd);
  prep_attdAT<<<(A_ * E_) / 256, 256, 0, stream>>>(W_attdAT, W_attd);
  prep_bias_p<<<G4 / 256, 256, 0, stream>>>(bias_p, b_ih, b_hh);
  hipMemsetAsync(rowsum, 0, (size_t)T_ * B_ * 4, stream);

  // --- precompute GEMMs (128-tile, K=512) ---
  gemm128<true, false><<<dim3(A_ / 128, G4 / 128), 256, 0, stream>>>(
      W_ih_p, W_attdAT, Wc, nullptr, A_, 512, 512, A_);
  gemm128<false, false><<<dim3(A_ / 128, MPRE / 128), 256, 0, stream>>>(
      xs_tb + (size_t)B_ * E_, W_attnE, preA, b_attn, A_, 512, 512, A_);
  gemm128<true, false><<<dim3(E_ / 128, MPRE / 128), 256, 0, stream>>>(
      xs_tb + (size_t)B_ * E_, W_attdE, pre_x2, b_attd, E_, 512, 512, E_);
  gemm128<false, false><<<dim3(G4 / 128, MPRE / 128), 256, 0, stream>>>(
      pre_x2, W_ih_p, preG, bias_p, G4, 512, 512, G4);
  // gates0 = features @ W_ih_p^T + bias_p (M=128 -> 64-tile)
  gemm_nt<false><<<dim3(G4 / 64, B_ / 64), 256, 0, stream>>>(
      xs_tb, W_ih_p, hWhh, bias_p, 512, 512, G4, 512);
  lstm0_pw<<<(B_ * H_) / 256, 256, 0, stream>>>(hWhh, c_st, h_all);

  // --- recurrence: 2 dispatches per step ---
  for (int t = 1; t <= T_; ++t) {
    step_hw<<<dim3(64, 2), 256, 0, stream>>>(
        h_all + (size_t)(t - 1) * BH, Whc,
        preA + (size_t)(t - 1) * B_ * A_, cnn, att, hWhh,
        rowsum + (size_t)(t - 1) * B_);
    step_gates<<<dim3(128, 2), 256, 0, stream>>>(
        att, Wc, preG + (size_t)(t - 1) * B_ * G4, hWhh,
        rowsum + (size_t)(t - 1) * B_, c_st, h_all + (size_t)t * BH);
  }

  // --- final projection: logits = hidden @ W_out^T + b_out  [4096, 10000] ---
  gemm128<false, true><<<dim3((V_ + 127) / 128, (TP1 * B_) / 128), 256, 0, stream>>>(
      h_all, W_out_b, logits, b_out, V_, 512, 512, V_);
}